// Round 6
// baseline (1654.214 us; speedup 1.0000x reference)
//
#include <hip/hip_runtime.h>
#include <math.h>

#define VEC   300
#define HID   256
#define ATT   500
#define NB    64
#define NS    128
#define G3    768     // 3*HID
#define GIC   1536    // both directions packed
#define H2    512     // 2*HID

typedef _Float16 half1;
typedef _Float16 h2_t __attribute__((ext_vector_type(2)));
typedef _Float16 h8_t __attribute__((ext_vector_type(8)));

__device__ __forceinline__ float sigm(float x){ return 1.0f/(1.0f+expf(-x)); }

// ---- prep: pack Whh into per-thread fp16 pair layout.
// Wpk[((dir*32+p)*3+j)*1024 + t] = {W[(j*256+u)*256 + ks*64+2p], W[...+1]}, u=t&255, ks=t>>8.
__global__ __launch_bounds__(256) void k_prep(const float* __restrict__ Wf,
                       const float* __restrict__ Wb, h2_t* __restrict__ Wpk){
  int o = blockIdx.x*256 + threadIdx.x;    // < 196608
  int t = o & 1023;
  int rest = o >> 10;                      // dir*96 + p*3 + j
  int j = rest % 3;
  int p = (rest/3) & 31;
  int dir = rest / 96;
  int u = t & 255, ks = t >> 8;
  const float* W = dir ? Wb : Wf;
  int k0 = ks*64 + 2*p;
  h2_t w;
  w.x = (half1)W[(j*HID+u)*HID + k0];
  w.y = (half1)W[(j*HID+u)*HID + k0 + 1];
  Wpk[o] = w;
}

// ---- prep2: per-thread-contiguous packing for the streamed variant.
// Spk[(dir*1024 + t)*64 + c] = weights for combo cc=36+c (pair 12+c/3, gate c%3), c<60; pad 0.
__global__ __launch_bounds__(256) void k_prep2(const float* __restrict__ Wf,
                       const float* __restrict__ Wb, h2_t* __restrict__ Spk){
  int o = blockIdx.x*256 + threadIdx.x;    // < 2*1024*64 = 131072
  int c = o & 63;
  int t = (o >> 6) & 1023;
  int dir = o >> 16;
  h2_t w; w.x = (half1)0.f; w.y = (half1)0.f;
  if (c < 60) {
    int p = 12 + c/3, j = c % 3;
    int u = t & 255, ks = t >> 8;
    int k0 = ks*64 + 2*p;
    const float* W = dir ? Wb : Wf;
    w.x = (half1)W[(j*HID+u)*HID + k0];
    w.y = (half1)W[(j*HID+u)*HID + k0 + 1];
  }
  Spk[o] = w;
}

// ---- input projection GEMM with fused embedding gather (fp32, unchanged).
#define BM 64
#define BN 128
#define BK 64
__global__ __launch_bounds__(256) void k_gi(const int* __restrict__ x,
      const float* __restrict__ emb,
      const float* __restrict__ Wf, const float* __restrict__ Wb,
      const float* __restrict__ bf, const float* __restrict__ bb,
      float* __restrict__ gi){
  __shared__ float As[BK][BM+4];
  __shared__ float Bs[BK][BN+4];
  __shared__ int   xi[BM];
  const int t = threadIdx.x;
  const int row0 = blockIdx.x * BM;
  const int col0 = blockIdx.y * BN;
  if (t < BM) {
    int i = row0 + t; int s = i >> 6; int b = i & 63;
    xi[t] = x[b*NS + s];
  }
  __syncthreads();
  float acc[4][8];
#pragma unroll
  for (int i = 0; i < 4; ++i)
#pragma unroll
    for (int j = 0; j < 8; ++j) acc[i][j] = 0.f;

  const int ty = t >> 4, tx = t & 15;
  for (int ks = 0; ks < 320; ks += BK) {
#pragma unroll
    for (int l = 0; l < 16; ++l) {
      int idx = l*256 + t;
      int r = idx >> 6, k = idx & 63;
      int kk = ks + k;
      As[k][r] = (kk < VEC) ? emb[(long)xi[r]*VEC + kk] : 0.f;
    }
#pragma unroll
    for (int l = 0; l < 32; ++l) {
      int idx = l*256 + t;
      int c = idx >> 6, k = idx & 63;
      int kk = ks + k;
      int g = col0 + c;
      float v = 0.f;
      if (kk < VEC) v = (g < G3) ? Wf[(long)g*VEC + kk] : Wb[(long)(g-G3)*VEC + kk];
      Bs[k][c] = v;
    }
    __syncthreads();
#pragma unroll 8
    for (int k = 0; k < BK; ++k) {
      float4 a4 = *reinterpret_cast<const float4*>(&As[k][ty*4]);
      float4 b0 = *reinterpret_cast<const float4*>(&Bs[k][tx*8]);
      float4 b1 = *reinterpret_cast<const float4*>(&Bs[k][tx*8+4]);
      float a[4] = {a4.x, a4.y, a4.z, a4.w};
      float bv[8] = {b0.x,b0.y,b0.z,b0.w,b1.x,b1.y,b1.z,b1.w};
#pragma unroll
      for (int i = 0; i < 4; ++i)
#pragma unroll
        for (int j = 0; j < 8; ++j) acc[i][j] += a[i]*bv[j];
    }
    __syncthreads();
  }
#pragma unroll
  for (int i = 0; i < 4; ++i) {
    int r = row0 + ty*4 + i;
#pragma unroll
    for (int j = 0; j < 8; ++j) {
      int g = col0 + tx*8 + j;
      float bias = (g < G3) ? bf[g] : bb[g-G3];
      gi[(long)r*GIC + g] = acc[i][j] + bias;
    }
  }
}

// ======== scan variant R: weights in 72 NAMED register scalars + 24 LDS combos.
#define RP(M) M(0) M(1) M(2) M(3) M(4) M(5) M(6) M(7) M(8) M(9) M(10) M(11) \
              M(12) M(13) M(14) M(15) M(16) M(17) M(18) M(19) M(20) M(21) M(22) M(23)

__global__ __launch_bounds__(1024)
__attribute__((amdgpu_num_vgpr(128)))
void k_scan_reg(const float* __restrict__ gi,
     const h2_t* __restrict__ Wpk,
     const float* __restrict__ bhf, const float* __restrict__ bhb,
     float* __restrict__ hseq){
  __shared__ float hl[260];
  __shared__ float part[256*13];
  __shared__ h2_t  lds_w[24*1024];     // pairs 24..31, 96KB
  const int t   = threadIdx.x;
  const int u   = t & 255;
  const int ks  = t >> 8;
  const int kb  = ks * 64;
  const int dir = blockIdx.x & 1;
  const int b   = blockIdx.x >> 1;
  const float* bhh = dir ? bhb : bhf;
  const h2_t* wp = Wpk + (long)dir*96*1024 + t;

#define DECLW(p) h2_t wA##p, wB##p, wC##p;
  RP(DECLW)
#define LOADW(p) wA##p = wp[((p)*3+0)*1024]; wB##p = wp[((p)*3+1)*1024]; wC##p = wp[((p)*3+2)*1024];
  RP(LOADW)
#pragma unroll
  for (int q = 0; q < 24; ++q)
    lds_w[q*1024 + t] = wp[(72+q)*1024];

  float bh0=0.f, bh1=0.f, bh2=0.f;
  if (ks == 0) { bh0 = bhh[u]; bh1 = bhh[HID+u]; bh2 = bhh[2*HID+u]; }
  if (t < 256) hl[t] = 0.f;
  __syncthreads();

#pragma unroll 1
  for (int tt = 0; tt < NS; ++tt) {
    const int s = dir ? (NS-1-tt) : tt;
    float i0=0.f, i1=0.f, i2=0.f;
    if (ks == 0) {
      long base = ((long)s*NB + b)*GIC + dir*G3 + u;
      i0 = gi[base]; i1 = gi[base+HID]; i2 = gi[base+2*HID];
    }
    float a0=0.f, a1=0.f, a2=0.f;
#define FMAW(p) { float2 hh = *reinterpret_cast<const float2*>(&hl[kb + 2*(p)]); \
    a0 += (float)wA##p.x*hh.x + (float)wA##p.y*hh.y; \
    a1 += (float)wB##p.x*hh.x + (float)wB##p.y*hh.y; \
    a2 += (float)wC##p.x*hh.x + (float)wC##p.y*hh.y; }
    RP(FMAW)
#pragma unroll
    for (int p = 0; p < 8; ++p) {       // LDS pairs (global 24..31): k = 48+2p
      float2 hh = *reinterpret_cast<const float2*>(&hl[kb + 48 + 2*p]);
      h2_t w0 = lds_w[(p*3+0)*1024 + t];
      h2_t w1 = lds_w[(p*3+1)*1024 + t];
      h2_t w2 = lds_w[(p*3+2)*1024 + t];
      a0 += (float)w0.x*hh.x + (float)w0.y*hh.y;
      a1 += (float)w1.x*hh.x + (float)w1.y*hh.y;
      a2 += (float)w2.x*hh.x + (float)w2.y*hh.y;
    }
    part[u*13 + ks*3 + 0] = a0;
    part[u*13 + ks*3 + 1] = a1;
    part[u*13 + ks*3 + 2] = a2;
    __syncthreads();
    if (ks == 0) {
      float g0 = bh0 + part[u*13+0] + part[u*13+3] + part[u*13+6] + part[u*13+9];
      float g1 = bh1 + part[u*13+1] + part[u*13+4] + part[u*13+7] + part[u*13+10];
      float g2 = bh2 + part[u*13+2] + part[u*13+5] + part[u*13+8] + part[u*13+11];
      float hc = hl[u];
      float r  = sigm(i0 + g0);
      float zg = sigm(i1 + g1);
      float n  = tanhf(i2 + r*g2);
      float hn = (1.f - zg)*n + zg*hc;
      hl[u] = hn;
      hseq[((long)b*NS + s)*H2 + dir*HID + u] = hn;
    }
    __syncthreads();
  }
}

// ======== scan variant S: 36 combos in LDS (144KB) + 60 combos re-streamed from L2
// each step (per-thread-contiguous Spk, 2-deep chunk pipeline). Fits in 64 VGPRs.
#define CONSE(Q,E,CC) \
    if ((CC) < 60) { \
      float2 hh = *reinterpret_cast<const float2*>(&hl[kb + 2*(12 + (CC)/3)]); \
      float v_ = (float)Q[2*(E)]*hh.x + (float)Q[2*(E)+1]*hh.y; \
      if ((CC)%3 == 0) a0 += v_; else if ((CC)%3 == 1) a1 += v_; else a2 += v_; \
    }
#define CONSL(Q,CC0) CONSE(Q,0,(CC0)+0) CONSE(Q,1,(CC0)+1) CONSE(Q,2,(CC0)+2) CONSE(Q,3,(CC0)+3)
#define CONSUME(C,q0,q1,q2,q3) { CONSL(q0,(C)*16+0) CONSL(q1,(C)*16+4) CONSL(q2,(C)*16+8) CONSL(q3,(C)*16+12) }

__global__ __launch_bounds__(1024)
void k_scan_stream(const float* __restrict__ gi,
     const h2_t* __restrict__ Wpk, const h2_t* __restrict__ Spk,
     const float* __restrict__ bhf, const float* __restrict__ bhb,
     float* __restrict__ hseq){
  __shared__ float hl[260];
  __shared__ float part[256*10 + 8];
  __shared__ h2_t  lds_w[36*1024];     // pairs 0..11, 144KB
  const int t   = threadIdx.x;
  const int u   = t & 255;
  const int ks  = t >> 8;
  const int kb  = ks * 64;
  const int dir = blockIdx.x & 1;
  const int b   = blockIdx.x >> 1;
  const float* bhh = dir ? bhb : bhf;
  const h2_t* wp = Wpk + (long)dir*96*1024 + t;
  const h8_t* sp = reinterpret_cast<const h8_t*>(Spk + ((long)dir*1024 + t)*64);

#pragma unroll
  for (int c = 0; c < 36; ++c)
    lds_w[c*1024 + t] = wp[c*1024];

  float bh0=0.f, bh1=0.f, bh2=0.f;
  if (ks == 0) { bh0 = bhh[u]; bh1 = bhh[HID+u]; bh2 = bhh[2*HID+u]; }
  if (t < 256) hl[t] = 0.f;
  __syncthreads();

#pragma unroll 1
  for (int tt = 0; tt < NS; ++tt) {
    const int s = dir ? (NS-1-tt) : tt;
    float i0=0.f, i1=0.f, i2=0.f;
    if (ks == 0) {
      long base = ((long)s*NB + b)*GIC + dir*G3 + u;
      i0 = gi[base]; i1 = gi[base+HID]; i2 = gi[base+2*HID];
    }
    h8_t A0,A1,A2,A3, B0,B1,B2,B3;
    A0 = sp[0]; A1 = sp[1]; A2 = sp[2]; A3 = sp[3];   // chunk 0 in flight
    float a0=0.f, a1=0.f, a2=0.f;
#pragma unroll
    for (int q = 0; q < 12; ++q) {      // LDS pairs 0..11: k = 2q, 2q+1
      float2 hh = *reinterpret_cast<const float2*>(&hl[kb + 2*q]);
      h2_t w0 = lds_w[(q*3+0)*1024 + t];
      h2_t w1 = lds_w[(q*3+1)*1024 + t];
      h2_t w2 = lds_w[(q*3+2)*1024 + t];
      a0 += (float)w0.x*hh.x + (float)w0.y*hh.y;
      a1 += (float)w1.x*hh.x + (float)w1.y*hh.y;
      a2 += (float)w2.x*hh.x + (float)w2.y*hh.y;
    }
    B0 = sp[4]; B1 = sp[5]; B2 = sp[6]; B3 = sp[7];   // chunk 1 in flight
    __builtin_amdgcn_sched_barrier(0);
    CONSUME(0, A0,A1,A2,A3)
    __builtin_amdgcn_sched_barrier(0);
    A0 = sp[8]; A1 = sp[9]; A2 = sp[10]; A3 = sp[11]; // chunk 2 in flight
    __builtin_amdgcn_sched_barrier(0);
    CONSUME(1, B0,B1,B2,B3)
    __builtin_amdgcn_sched_barrier(0);
    B0 = sp[12]; B1 = sp[13]; B2 = sp[14]; B3 = sp[15]; // chunk 3 in flight
    __builtin_amdgcn_sched_barrier(0);
    CONSUME(2, A0,A1,A2,A3)
    __builtin_amdgcn_sched_barrier(0);
    CONSUME(3, B0,B1,B2,B3)

    if (ks > 0) {
      part[u*10 + (ks-1)*3 + 0] = a0;
      part[u*10 + (ks-1)*3 + 1] = a1;
      part[u*10 + (ks-1)*3 + 2] = a2;
    }
    __syncthreads();
    if (ks == 0) {
      float g0 = bh0 + a0 + part[u*10+0] + part[u*10+3] + part[u*10+6];
      float g1 = bh1 + a1 + part[u*10+1] + part[u*10+4] + part[u*10+7];
      float g2 = bh2 + a2 + part[u*10+2] + part[u*10+5] + part[u*10+8];
      float hc = hl[u];
      float r  = sigm(i0 + g0);
      float zg = sigm(i1 + g1);
      float n  = tanhf(i2 + r*g2);
      float hn = (1.f - zg)*n + zg*hc;
      hl[u] = hn;
      hseq[((long)b*NS + s)*H2 + dir*HID + u] = hn;
    }
    __syncthreads();
  }
}

// ---- attention scores u[b][s] = sum_a tanh(h.W_a + ab_a) * aw[z[b]][a]
__global__ __launch_bounds__(256) void k_att1(const float* __restrict__ hseq,
    const float* __restrict__ afW, const float* __restrict__ afb,
    const float* __restrict__ attw, const int* __restrict__ z,
    float* __restrict__ ub){
  __shared__ float ht[16][H2];
  __shared__ float red[16][260];
  const int t  = threadIdx.x;
  const int b  = blockIdx.x >> 3;
  const int s0 = (blockIdx.x & 7) * 16;
#pragma unroll
  for (int l = 0; l < 32; ++l) {
    int idx = l*256 + t; int sr = idx >> 9; int c = idx & 511;
    ht[sr][c] = hseq[((long)b*NS + s0+sr)*H2 + c];
  }
  __syncthreads();
  float us[16];
#pragma unroll
  for (int s = 0; s < 16; ++s) us[s] = 0.f;
  const int zb = z[b];
  for (int rep = 0; rep < 2; ++rep) {
    int a = rep*256 + t;
    if (a < ATT) {
      const float* wr = afW + (long)a*H2;
      float ab = afb[a];
      float aw = attw[zb*ATT + a];
      float d[16];
#pragma unroll
      for (int s = 0; s < 16; ++s) d[s] = ab;
      for (int h = 0; h < H2; h += 4) {
        float4 w4 = *reinterpret_cast<const float4*>(wr + h);
#pragma unroll
        for (int s = 0; s < 16; ++s) {
          float4 hv = *reinterpret_cast<const float4*>(&ht[s][h]);
          d[s] += w4.x*hv.x + w4.y*hv.y + w4.z*hv.z + w4.w*hv.w;
        }
      }
#pragma unroll
      for (int s = 0; s < 16; ++s) us[s] += tanhf(d[s]) * aw;
    }
  }
#pragma unroll
  for (int s = 0; s < 16; ++s) red[s][t] = us[s];
  __syncthreads();
  for (int off = 128; off >= 1; off >>= 1) {
    if (t < off) {
#pragma unroll
      for (int s = 0; s < 16; ++s) red[s][t] += red[s][t+off];
    }
    __syncthreads();
  }
  if (t < 16) ub[b*NS + s0 + t] = red[t][0];
}

// ---- softmax + pooled + fc
__global__ __launch_bounds__(256) void k_att2(const float* __restrict__ hseq,
   const float* __restrict__ ub, const float* __restrict__ fcW,
   const float* __restrict__ fcb, float* __restrict__ out){
  __shared__ float att[NS];
  __shared__ float red[256];
  __shared__ float pool[H2];
  const int t = threadIdx.x, b = blockIdx.x;
  float v = (t < NS) ? ub[b*NS + t] : -3.4e38f;
  red[t] = v; __syncthreads();
  for (int off = 128; off >= 1; off >>= 1) {
    if (t < off) red[t] = fmaxf(red[t], red[t+off]);
    __syncthreads();
  }
  float mx = red[0]; __syncthreads();
  float e = (t < NS) ? expf(v - mx) : 0.f;
  red[t] = e; __syncthreads();
  for (int off = 128; off >= 1; off >>= 1) {
    if (t < off) red[t] += red[t+off];
    __syncthreads();
  }
  float sm = red[0]; __syncthreads();
  if (t < NS) att[t] = e / sm;
  __syncthreads();
#pragma unroll
  for (int rep = 0; rep < 2; ++rep) {
    int c = rep*256 + t;
    float acc = 0.f;
#pragma unroll 4
    for (int s = 0; s < NS; ++s) acc += att[s] * hseq[((long)b*NS + s)*H2 + c];
    pool[c] = acc;
  }
  __syncthreads();
  for (int j = 0; j < 2; ++j) {
    float p = pool[t]*fcW[j*H2+t] + pool[t+256]*fcW[j*H2+t+256];
    red[t] = p; __syncthreads();
    for (int off = 128; off >= 1; off >>= 1) {
      if (t < off) red[t] += red[t+off];
      __syncthreads();
    }
    if (t == 0) out[b*2+j] = red[0] + fcb[j];
    __syncthreads();
  }
}

extern "C" void kernel_launch(void* const* d_in, const int* in_sizes, int n_in,
                              void* d_out, int out_size, void* d_ws, size_t ws_size,
                              hipStream_t stream) {
  const int*   x     = (const int*)  d_in[0];
  const int*   z     = (const int*)  d_in[1];
  const float* emb   = (const float*)d_in[2];
  const float* Wih_f = (const float*)d_in[3];
  const float* Whh_f = (const float*)d_in[4];
  const float* bih_f = (const float*)d_in[5];
  const float* bhh_f = (const float*)d_in[6];
  const float* Wih_b = (const float*)d_in[7];
  const float* Whh_b = (const float*)d_in[8];
  const float* bih_b = (const float*)d_in[9];
  const float* bhh_b = (const float*)d_in[10];
  const float* afW   = (const float*)d_in[11];
  const float* afb   = (const float*)d_in[12];
  const float* attw  = (const float*)d_in[13];
  const float* fcW   = (const float*)d_in[14];
  const float* fcb   = (const float*)d_in[15];

  float* ws   = (float*)d_ws;
  h2_t* Wpk   = (h2_t*)ws;               // 196608 * 4B
  h2_t* Spk   = (h2_t*)(ws + 196608);    // 131072 * 4B
  float* giW  = ws   + 196608 + 131072;  // 8192*1536
  float* hseq = giW  + 12582912;         // 64*128*512
  float* ubuf = hseq + 4194304;          // 64*128

  k_prep <<<dim3(768), dim3(256), 0, stream>>>(Whh_f, Whh_b, Wpk);
  k_prep2<<<dim3(512), dim3(256), 0, stream>>>(Whh_f, Whh_b, Spk);
  k_gi   <<<dim3(128,12), dim3(256), 0, stream>>>(x, emb, Wih_f, Wih_b, bih_f, bih_b, giW);

  // Pick the register-resident scan iff it truly allocated without scratch spill.
  hipFuncAttributes fa;
  bool useReg = false;
  if (hipFuncGetAttributes(&fa, reinterpret_cast<const void*>(k_scan_reg)) == hipSuccess)
    useReg = (fa.localSizeBytes == 0);
  if (useReg)
    k_scan_reg   <<<dim3(128), dim3(1024), 0, stream>>>(giW, Wpk, bhh_f, bhh_b, hseq);
  else
    k_scan_stream<<<dim3(128), dim3(1024), 0, stream>>>(giW, Wpk, Spk, bhh_f, bhh_b, hseq);

  k_att1<<<dim3(512),  dim3(256), 0, stream>>>(hseq, afW, afb, attw, z, ubuf);
  k_att2<<<dim3(64),   dim3(256), 0, stream>>>(hseq, ubuf, fcW, fcb, (float*)d_out);
}

// Round 7
// 517.767 us; speedup vs baseline: 3.1949x; 3.1949x over previous
//
#include <hip/hip_runtime.h>
#include <math.h>

#define VEC   300
#define HID   256
#define ATT   500
#define NB    64
#define NS    128
#define G3    768     // 3*HID
#define GIC   1536    // both directions packed
#define H2    512     // 2*HID

typedef _Float16 half1;
typedef _Float16 h2_t __attribute__((ext_vector_type(2)));

__device__ __forceinline__ float sigm(float x){ return 1.0f/(1.0f+expf(-x)); }

#if __has_builtin(__builtin_amdgcn_fdot2)
#define FDOT(w,h,acc) __builtin_amdgcn_fdot2((w),(h),(acc),false)
#else
#define FDOT(w,h,acc) ((acc) + (float)(w).x*(float)(h).x + (float)(w).y*(float)(h).y)
#endif

// ---- prep: pack Whh into per-thread fp16 pair layout.
// Wpk[((dir*32+p)*3+j)*1024 + t] = {W[(j*256+u)*256 + ks*64+2p], W[...+1]}, u=t&255, ks=t>>8.
__global__ __launch_bounds__(256) void k_prep(const float* __restrict__ Wf,
                       const float* __restrict__ Wb, h2_t* __restrict__ Wpk){
  int o = blockIdx.x*256 + threadIdx.x;    // < 196608
  int t = o & 1023;
  int rest = o >> 10;                      // dir*96 + p*3 + j
  int j = rest % 3;
  int p = (rest/3) & 31;
  int dir = rest / 96;
  int u = t & 255, ks = t >> 8;
  const float* W = dir ? Wb : Wf;
  int k0 = ks*64 + 2*p;
  h2_t w;
  w.x = (half1)W[(j*HID+u)*HID + k0];
  w.y = (half1)W[(j*HID+u)*HID + k0 + 1];
  Wpk[o] = w;
}

// ---- input projection GEMM with fused embedding gather (fp32, unchanged).
#define BM 64
#define BN 128
#define BK 64
__global__ __launch_bounds__(256) void k_gi(const int* __restrict__ x,
      const float* __restrict__ emb,
      const float* __restrict__ Wf, const float* __restrict__ Wb,
      const float* __restrict__ bf, const float* __restrict__ bb,
      float* __restrict__ gi){
  __shared__ float As[BK][BM+4];
  __shared__ float Bs[BK][BN+4];
  __shared__ int   xi[BM];
  const int t = threadIdx.x;
  const int row0 = blockIdx.x * BM;
  const int col0 = blockIdx.y * BN;
  if (t < BM) {
    int i = row0 + t; int s = i >> 6; int b = i & 63;
    xi[t] = x[b*NS + s];
  }
  __syncthreads();
  float acc[4][8];
#pragma unroll
  for (int i = 0; i < 4; ++i)
#pragma unroll
    for (int j = 0; j < 8; ++j) acc[i][j] = 0.f;

  const int ty = t >> 4, tx = t & 15;
  for (int ks = 0; ks < 320; ks += BK) {
#pragma unroll
    for (int l = 0; l < 16; ++l) {
      int idx = l*256 + t;
      int r = idx >> 6, k = idx & 63;
      int kk = ks + k;
      As[k][r] = (kk < VEC) ? emb[(long)xi[r]*VEC + kk] : 0.f;
    }
#pragma unroll
    for (int l = 0; l < 32; ++l) {
      int idx = l*256 + t;
      int c = idx >> 6, k = idx & 63;
      int kk = ks + k;
      int g = col0 + c;
      float v = 0.f;
      if (kk < VEC) v = (g < G3) ? Wf[(long)g*VEC + kk] : Wb[(long)(g-G3)*VEC + kk];
      Bs[k][c] = v;
    }
    __syncthreads();
#pragma unroll 8
    for (int k = 0; k < BK; ++k) {
      float4 a4 = *reinterpret_cast<const float4*>(&As[k][ty*4]);
      float4 b0 = *reinterpret_cast<const float4*>(&Bs[k][tx*8]);
      float4 b1 = *reinterpret_cast<const float4*>(&Bs[k][tx*8+4]);
      float a[4] = {a4.x, a4.y, a4.z, a4.w};
      float bv[8] = {b0.x,b0.y,b0.z,b0.w,b1.x,b1.y,b1.z,b1.w};
#pragma unroll
      for (int i = 0; i < 4; ++i)
#pragma unroll
        for (int j = 0; j < 8; ++j) acc[i][j] += a[i]*bv[j];
    }
    __syncthreads();
  }
#pragma unroll
  for (int i = 0; i < 4; ++i) {
    int r = row0 + ty*4 + i;
#pragma unroll
    for (int j = 0; j < 8; ++j) {
      int g = col0 + tx*8 + j;
      float bias = (g < G3) ? bf[g] : bb[g-G3];
      gi[(long)r*GIC + g] = acc[i][j] + bias;
    }
  }
}

// ======== GRU scan: weights in 72 NAMED register h2_t scalars + 24 combos in LDS.
// 1024 thr = 256 u x 4 ks; one (b,dir) per WG -> 128 WGs. fdot2 (2 MAC/instr) on
// packed fp16 h. waves_per_eu(4,4): LDS (111KB) forces 1 WG/CU = 4 waves/EU anyway,
// so pin allocator to the 128-VGPR budget. Launched UNCONDITIONALLY this round so
// rocprof reports its true VGPR_Count / scratch behavior.
#define RP(M) M(0) M(1) M(2) M(3) M(4) M(5) M(6) M(7) M(8) M(9) M(10) M(11) \
              M(12) M(13) M(14) M(15) M(16) M(17) M(18) M(19) M(20) M(21) M(22) M(23)

__global__ __launch_bounds__(1024)
__attribute__((amdgpu_waves_per_eu(4, 4)))
void k_scan_reg(const float* __restrict__ gi,
     const h2_t* __restrict__ Wpk,
     const float* __restrict__ bhf, const float* __restrict__ bhb,
     float* __restrict__ hseq){
  __shared__ float hl[260];
  __shared__ half1 hl16[260];
  __shared__ float part[256*13];
  __shared__ h2_t  lds_w[24*1024];     // pairs 24..31, 96KB
  const int t   = threadIdx.x;
  const int u   = t & 255;
  const int ks  = t >> 8;
  const int kb  = ks * 64;
  const int dir = blockIdx.x & 1;
  const int b   = blockIdx.x >> 1;
  const float* bhh = dir ? bhb : bhf;
  const h2_t* wp = Wpk + (long)dir*96*1024 + t;

#define DECLW(p) h2_t wA##p, wB##p, wC##p;
  RP(DECLW)
#define LOADW(p) wA##p = wp[((p)*3+0)*1024]; wB##p = wp[((p)*3+1)*1024]; wC##p = wp[((p)*3+2)*1024];
  RP(LOADW)
#pragma unroll
  for (int q = 0; q < 24; ++q)
    lds_w[q*1024 + t] = wp[(72+q)*1024];

  float bh0=0.f, bh1=0.f, bh2=0.f;
  if (ks == 0) { bh0 = bhh[u]; bh1 = bhh[HID+u]; bh2 = bhh[2*HID+u]; }
  if (t < 256) { hl[t] = 0.f; hl16[t] = (half1)0.f; }
  __syncthreads();

#pragma unroll 1
  for (int tt = 0; tt < NS; ++tt) {
    const int s = dir ? (NS-1-tt) : tt;
    float i0=0.f, i1=0.f, i2=0.f;
    if (ks == 0) {
      long base = ((long)s*NB + b)*GIC + dir*G3 + u;
      i0 = gi[base]; i1 = gi[base+HID]; i2 = gi[base+2*HID];
    }
    float a0=0.f, a1=0.f, a2=0.f;
#define FMAW(p) { h2_t hh = *reinterpret_cast<const h2_t*>(&hl16[kb + 2*(p)]); \
    a0 = FDOT(wA##p, hh, a0); a1 = FDOT(wB##p, hh, a1); a2 = FDOT(wC##p, hh, a2); }
    RP(FMAW)
#pragma unroll
    for (int p = 0; p < 8; ++p) {       // LDS pairs (global 24..31): k = 48+2p
      h2_t hh = *reinterpret_cast<const h2_t*>(&hl16[kb + 48 + 2*p]);
      h2_t w0 = lds_w[(p*3+0)*1024 + t];
      h2_t w1 = lds_w[(p*3+1)*1024 + t];
      h2_t w2 = lds_w[(p*3+2)*1024 + t];
      a0 = FDOT(w0, hh, a0);
      a1 = FDOT(w1, hh, a1);
      a2 = FDOT(w2, hh, a2);
    }
    part[u*13 + ks*3 + 0] = a0;
    part[u*13 + ks*3 + 1] = a1;
    part[u*13 + ks*3 + 2] = a2;
    __syncthreads();
    if (ks == 0) {
      float g0 = bh0 + part[u*13+0] + part[u*13+3] + part[u*13+6] + part[u*13+9];
      float g1 = bh1 + part[u*13+1] + part[u*13+4] + part[u*13+7] + part[u*13+10];
      float g2 = bh2 + part[u*13+2] + part[u*13+5] + part[u*13+8] + part[u*13+11];
      float hc = hl[u];
      float r  = sigm(i0 + g0);
      float zg = sigm(i1 + g1);
      float n  = tanhf(i2 + r*g2);
      float hn = (1.f - zg)*n + zg*hc;
      hl[u] = hn;
      hl16[u] = (half1)hn;
      hseq[((long)b*NS + s)*H2 + dir*HID + u] = hn;
    }
    __syncthreads();
  }
}

// ---- attention scores u[b][s] = sum_a tanh(h.W_a + ab_a) * aw[z[b]][a]
__global__ __launch_bounds__(256) void k_att1(const float* __restrict__ hseq,
    const float* __restrict__ afW, const float* __restrict__ afb,
    const float* __restrict__ attw, const int* __restrict__ z,
    float* __restrict__ ub){
  __shared__ float ht[16][H2];
  __shared__ float red[16][260];
  const int t  = threadIdx.x;
  const int b  = blockIdx.x >> 3;
  const int s0 = (blockIdx.x & 7) * 16;
#pragma unroll
  for (int l = 0; l < 32; ++l) {
    int idx = l*256 + t; int sr = idx >> 9; int c = idx & 511;
    ht[sr][c] = hseq[((long)b*NS + s0+sr)*H2 + c];
  }
  __syncthreads();
  float us[16];
#pragma unroll
  for (int s = 0; s < 16; ++s) us[s] = 0.f;
  const int zb = z[b];
  for (int rep = 0; rep < 2; ++rep) {
    int a = rep*256 + t;
    if (a < ATT) {
      const float* wr = afW + (long)a*H2;
      float ab = afb[a];
      float aw = attw[zb*ATT + a];
      float d[16];
#pragma unroll
      for (int s = 0; s < 16; ++s) d[s] = ab;
      for (int h = 0; h < H2; h += 4) {
        float4 w4 = *reinterpret_cast<const float4*>(wr + h);
#pragma unroll
        for (int s = 0; s < 16; ++s) {
          float4 hv = *reinterpret_cast<const float4*>(&ht[s][h]);
          d[s] += w4.x*hv.x + w4.y*hv.y + w4.z*hv.z + w4.w*hv.w;
        }
      }
#pragma unroll
      for (int s = 0; s < 16; ++s) us[s] += tanhf(d[s]) * aw;
    }
  }
#pragma unroll
  for (int s = 0; s < 16; ++s) red[s][t] = us[s];
  __syncthreads();
  for (int off = 128; off >= 1; off >>= 1) {
    if (t < off) {
#pragma unroll
      for (int s = 0; s < 16; ++s) red[s][t] += red[s][t+off];
    }
    __syncthreads();
  }
  if (t < 16) ub[b*NS + s0 + t] = red[t][0];
}

// ---- softmax + pooled + fc
__global__ __launch_bounds__(256) void k_att2(const float* __restrict__ hseq,
   const float* __restrict__ ub, const float* __restrict__ fcW,
   const float* __restrict__ fcb, float* __restrict__ out){
  __shared__ float att[NS];
  __shared__ float red[256];
  __shared__ float pool[H2];
  const int t = threadIdx.x, b = blockIdx.x;
  float v = (t < NS) ? ub[b*NS + t] : -3.4e38f;
  red[t] = v; __syncthreads();
  for (int off = 128; off >= 1; off >>= 1) {
    if (t < off) red[t] = fmaxf(red[t], red[t+off]);
    __syncthreads();
  }
  float mx = red[0]; __syncthreads();
  float e = (t < NS) ? expf(v - mx) : 0.f;
  red[t] = e; __syncthreads();
  for (int off = 128; off >= 1; off >>= 1) {
    if (t < off) red[t] += red[t+off];
    __syncthreads();
  }
  float sm = red[0]; __syncthreads();
  if (t < NS) att[t] = e / sm;
  __syncthreads();
#pragma unroll
  for (int rep = 0; rep < 2; ++rep) {
    int c = rep*256 + t;
    float acc = 0.f;
#pragma unroll 4
    for (int s = 0; s < NS; ++s) acc += att[s] * hseq[((long)b*NS + s)*H2 + c];
    pool[c] = acc;
  }
  __syncthreads();
  for (int j = 0; j < 2; ++j) {
    float p = pool[t]*fcW[j*H2+t] + pool[t+256]*fcW[j*H2+t+256];
    red[t] = p; __syncthreads();
    for (int off = 128; off >= 1; off >>= 1) {
      if (t < off) red[t] += red[t+off];
      __syncthreads();
    }
    if (t == 0) out[b*2+j] = red[0] + fcb[j];
    __syncthreads();
  }
}

extern "C" void kernel_launch(void* const* d_in, const int* in_sizes, int n_in,
                              void* d_out, int out_size, void* d_ws, size_t ws_size,
                              hipStream_t stream) {
  const int*   x     = (const int*)  d_in[0];
  const int*   z     = (const int*)  d_in[1];
  const float* emb   = (const float*)d_in[2];
  const float* Wih_f = (const float*)d_in[3];
  const float* Whh_f = (const float*)d_in[4];
  const float* bih_f = (const float*)d_in[5];
  const float* bhh_f = (const float*)d_in[6];
  const float* Wih_b = (const float*)d_in[7];
  const float* Whh_b = (const float*)d_in[8];
  const float* bih_b = (const float*)d_in[9];
  const float* bhh_b = (const float*)d_in[10];
  const float* afW   = (const float*)d_in[11];
  const float* afb   = (const float*)d_in[12];
  const float* attw  = (const float*)d_in[13];
  const float* fcW   = (const float*)d_in[14];
  const float* fcb   = (const float*)d_in[15];

  float* ws   = (float*)d_ws;
  h2_t* Wpk   = (h2_t*)ws;               // 196608 * 4B
  float* giW  = ws   + 196608;           // 8192*1536
  float* hseq = giW  + 12582912;         // 64*128*512
  float* ubuf = hseq + 4194304;          // 64*128

  k_prep<<<dim3(768), dim3(256), 0, stream>>>(Whh_f, Whh_b, Wpk);
  k_gi  <<<dim3(128,12), dim3(256), 0, stream>>>(x, emb, Wih_f, Wih_b, bih_f, bih_b, giW);
  k_scan_reg<<<dim3(128), dim3(1024), 0, stream>>>(giW, Wpk, bhh_f, bhh_b, hseq);
  k_att1<<<dim3(512),  dim3(256), 0, stream>>>(hseq, afW, afb, attw, z, ubuf);
  k_att2<<<dim3(64),   dim3(256), 0, stream>>>(hseq, ubuf, fcW, fcb, (float*)d_out);
}

// Round 8
// 366.181 us; speedup vs baseline: 4.5175x; 1.4140x over previous
//
#include <hip/hip_runtime.h>
#include <math.h>

#define VEC   300
#define HID   256
#define ATT   500
#define NB    64
#define NS    128
#define G3    768     // 3*HID
#define GIC   1536    // both directions packed
#define H2    512     // 2*HID

typedef _Float16 half1;
typedef _Float16 h2_t  __attribute__((ext_vector_type(2)));
typedef _Float16 f16x8 __attribute__((ext_vector_type(8)));
typedef float    f32x4 __attribute__((ext_vector_type(4)));

__device__ __forceinline__ float sigm(float x){ return 1.0f/(1.0f+expf(-x)); }

#if __has_builtin(__builtin_amdgcn_fdot2)
#define FDOT(w,h,acc) __builtin_amdgcn_fdot2((w),(h),(acc),false)
#else
#define FDOT(w,h,acc) ((acc) + (float)(w).x*(float)(h).x + (float)(w).y*(float)(h).y)
#endif

// ---- prep: pack Whh into per-thread fp16 pair layout.
// Wpk[((dir*32+p)*3+j)*1024 + t] = {W[(j*256+u)*256 + ks*64+2p], W[...+1]}, u=t&255, ks=t>>8.
__global__ __launch_bounds__(256) void k_prep(const float* __restrict__ Wf,
                       const float* __restrict__ Wb, h2_t* __restrict__ Wpk){
  int o = blockIdx.x*256 + threadIdx.x;    // < 196608
  int t = o & 1023;
  int rest = o >> 10;                      // dir*96 + p*3 + j
  int j = rest % 3;
  int p = (rest/3) & 31;
  int dir = rest / 96;
  int u = t & 255, ks = t >> 8;
  const float* W = dir ? Wb : Wf;
  int k0 = ks*64 + 2*p;
  h2_t w;
  w.x = (half1)W[(j*HID+u)*HID + k0];
  w.y = (half1)W[(j*HID+u)*HID + k0 + 1];
  Wpk[o] = w;
}

// ---- input projection: fp16 MFMA GEMM with fused embedding gather.
// C[i][g], i = s*64+b (8192 rows), g in [0,1536). Block tile 128x128, 4 waves 2x2,
// wave tile 64x64 (16 MFMA 16x16x32 per K-step), K = 300 padded to 320 (10 steps).
__global__ __launch_bounds__(256)
__attribute__((amdgpu_waves_per_eu(4, 4)))
void k_gi_mfma(const int* __restrict__ x,
      const float* __restrict__ emb,
      const float* __restrict__ Wf, const float* __restrict__ Wb,
      const float* __restrict__ bf, const float* __restrict__ bb,
      float* __restrict__ gi){
  __shared__ half1 Al[128*40];   // [row][k] pad 40 halves (80B = 5x16B, b128-aligned)
  __shared__ half1 Bl[128*40];   // [gcol_local][k]
  __shared__ int   xi[128];
  const int t = threadIdx.x;
  const int row0 = blockIdx.x * 128;
  const int col0 = blockIdx.y * 128;
  if (t < 128) {
    int i = row0 + t; int s = i >> 6; int b = i & 63;
    xi[t] = x[b*NS + s];
  }
  __syncthreads();

  const int lane = t & 63, wid = t >> 6;
  const int wr = wid >> 1, wc = wid & 1;
  const int l15 = lane & 15, lk = lane >> 4;

  f32x4 acc[4][4];
#pragma unroll
  for (int i = 0; i < 4; ++i)
#pragma unroll
    for (int j = 0; j < 4; ++j) acc[i][j] = (f32x4){0.f,0.f,0.f,0.f};

  for (int ks = 0; ks < 10; ++ks) {
#pragma unroll
    for (int l = 0; l < 8; ++l) {            // stage A and B: 2048 h2-pairs each
      int idx = l*256 + t;
      int row = idx >> 4;                    // 0..127
      int kp  = idx & 15;                    // k-pair 0..15
      int kk  = ks*32 + kp*2;
      h2_t va; va.x = (half1)0.f; va.y = (half1)0.f;
      h2_t vb; vb.x = (half1)0.f; vb.y = (half1)0.f;
      if (kk < VEC) {
        float2 e = *reinterpret_cast<const float2*>(&emb[(long)xi[row]*VEC + kk]);
        va.x = (half1)e.x; va.y = (half1)e.y;
        int g = col0 + row;
        const float* W = (g < G3) ? &Wf[(long)g*VEC] : &Wb[(long)(g-G3)*VEC];
        float2 w2 = *reinterpret_cast<const float2*>(&W[kk]);
        vb.x = (half1)w2.x; vb.y = (half1)w2.y;
      }
      *reinterpret_cast<h2_t*>(&Al[row*40 + kp*2]) = va;
      *reinterpret_cast<h2_t*>(&Bl[row*40 + kp*2]) = vb;
    }
    __syncthreads();
    f16x8 af[4], bfq[4];
#pragma unroll
    for (int i = 0; i < 4; ++i)
      af[i]  = *reinterpret_cast<const f16x8*>(&Al[(wr*64 + i*16 + l15)*40 + lk*8]);
#pragma unroll
    for (int j = 0; j < 4; ++j)
      bfq[j] = *reinterpret_cast<const f16x8*>(&Bl[(wc*64 + j*16 + l15)*40 + lk*8]);
#pragma unroll
    for (int i = 0; i < 4; ++i)
#pragma unroll
      for (int j = 0; j < 4; ++j)
        acc[i][j] = __builtin_amdgcn_mfma_f32_16x16x32_f16(af[i], bfq[j], acc[i][j], 0, 0, 0);
    __syncthreads();
  }

  // epilogue: C row = (lane>>4)*4 + reg, col = lane&15 (m89-verified mapping)
#pragma unroll
  for (int j = 0; j < 4; ++j) {
    int gcol = col0 + wc*64 + j*16 + l15;
    float bj = (gcol < G3) ? bf[gcol] : bb[gcol - G3];
#pragma unroll
    for (int i = 0; i < 4; ++i) {
      int grow0 = row0 + wr*64 + i*16 + lk*4;
#pragma unroll
      for (int q = 0; q < 4; ++q)
        gi[(long)(grow0 + q)*GIC + gcol] = acc[i][j][q] + bj;
    }
  }
}

// ======== GRU scan: weights in 72 NAMED register h2_t scalars + 24 combos in LDS.
#define RP(M) M(0) M(1) M(2) M(3) M(4) M(5) M(6) M(7) M(8) M(9) M(10) M(11) \
              M(12) M(13) M(14) M(15) M(16) M(17) M(18) M(19) M(20) M(21) M(22) M(23)

__global__ __launch_bounds__(1024)
__attribute__((amdgpu_waves_per_eu(4, 4)))
void k_scan_reg(const float* __restrict__ gi,
     const h2_t* __restrict__ Wpk,
     const float* __restrict__ bhf, const float* __restrict__ bhb,
     float* __restrict__ hseq){
  __shared__ float hl[260];
  __shared__ half1 hl16[260];
  __shared__ float part[256*13];
  __shared__ h2_t  lds_w[24*1024];     // pairs 24..31, 96KB
  const int t   = threadIdx.x;
  const int u   = t & 255;
  const int ks  = t >> 8;
  const int kb  = ks * 64;
  const int dir = blockIdx.x & 1;
  const int b   = blockIdx.x >> 1;
  const float* bhh = dir ? bhb : bhf;
  const h2_t* wp = Wpk + (long)dir*96*1024 + t;

#define DECLW(p) h2_t wA##p, wB##p, wC##p;
  RP(DECLW)
#define LOADW(p) wA##p = wp[((p)*3+0)*1024]; wB##p = wp[((p)*3+1)*1024]; wC##p = wp[((p)*3+2)*1024];
  RP(LOADW)
#pragma unroll
  for (int q = 0; q < 24; ++q)
    lds_w[q*1024 + t] = wp[(72+q)*1024];

  float bh0=0.f, bh1=0.f, bh2=0.f;
  if (ks == 0) { bh0 = bhh[u]; bh1 = bhh[HID+u]; bh2 = bhh[2*HID+u]; }
  if (t < 256) { hl[t] = 0.f; hl16[t] = (half1)0.f; }
  __syncthreads();

#pragma unroll 1
  for (int tt = 0; tt < NS; ++tt) {
    const int s = dir ? (NS-1-tt) : tt;
    float i0=0.f, i1=0.f, i2=0.f;
    if (ks == 0) {
      long base = ((long)s*NB + b)*GIC + dir*G3 + u;
      i0 = gi[base]; i1 = gi[base+HID]; i2 = gi[base+2*HID];
    }
    float a0=0.f, a1=0.f, a2=0.f;
#define FMAW(p) { h2_t hh = *reinterpret_cast<const h2_t*>(&hl16[kb + 2*(p)]); \
    a0 = FDOT(wA##p, hh, a0); a1 = FDOT(wB##p, hh, a1); a2 = FDOT(wC##p, hh, a2); }
    RP(FMAW)
#pragma unroll
    for (int p = 0; p < 8; ++p) {       // LDS pairs (global 24..31): k = 48+2p
      h2_t hh = *reinterpret_cast<const h2_t*>(&hl16[kb + 48 + 2*p]);
      h2_t w0 = lds_w[(p*3+0)*1024 + t];
      h2_t w1 = lds_w[(p*3+1)*1024 + t];
      h2_t w2 = lds_w[(p*3+2)*1024 + t];
      a0 = FDOT(w0, hh, a0);
      a1 = FDOT(w1, hh, a1);
      a2 = FDOT(w2, hh, a2);
    }
    part[u*13 + ks*3 + 0] = a0;
    part[u*13 + ks*3 + 1] = a1;
    part[u*13 + ks*3 + 2] = a2;
    __syncthreads();
    if (ks == 0) {
      float g0 = bh0 + part[u*13+0] + part[u*13+3] + part[u*13+6] + part[u*13+9];
      float g1 = bh1 + part[u*13+1] + part[u*13+4] + part[u*13+7] + part[u*13+10];
      float g2 = bh2 + part[u*13+2] + part[u*13+5] + part[u*13+8] + part[u*13+11];
      float hc = hl[u];
      float r  = sigm(i0 + g0);
      float zg = sigm(i1 + g1);
      float n  = tanhf(i2 + r*g2);
      float hn = (1.f - zg)*n + zg*hc;
      hl[u] = hn;
      hl16[u] = (half1)hn;
      hseq[((long)b*NS + s)*H2 + dir*HID + u] = hn;
    }
    __syncthreads();
  }
}

// ---- attention scores u[b][s] = sum_a tanh(h.W_a + ab_a) * aw[z[b]][a]
__global__ __launch_bounds__(256) void k_att1(const float* __restrict__ hseq,
    const float* __restrict__ afW, const float* __restrict__ afb,
    const float* __restrict__ attw, const int* __restrict__ z,
    float* __restrict__ ub){
  __shared__ float ht[16][H2];
  __shared__ float red[16][260];
  const int t  = threadIdx.x;
  const int b  = blockIdx.x >> 3;
  const int s0 = (blockIdx.x & 7) * 16;
#pragma unroll
  for (int l = 0; l < 32; ++l) {
    int idx = l*256 + t; int sr = idx >> 9; int c = idx & 511;
    ht[sr][c] = hseq[((long)b*NS + s0+sr)*H2 + c];
  }
  __syncthreads();
  float us[16];
#pragma unroll
  for (int s = 0; s < 16; ++s) us[s] = 0.f;
  const int zb = z[b];
  for (int rep = 0; rep < 2; ++rep) {
    int a = rep*256 + t;
    if (a < ATT) {
      const float* wr = afW + (long)a*H2;
      float ab = afb[a];
      float aw = attw[zb*ATT + a];
      float d[16];
#pragma unroll
      for (int s = 0; s < 16; ++s) d[s] = ab;
      for (int h = 0; h < H2; h += 4) {
        float4 w4 = *reinterpret_cast<const float4*>(wr + h);
#pragma unroll
        for (int s = 0; s < 16; ++s) {
          float4 hv = *reinterpret_cast<const float4*>(&ht[s][h]);
          d[s] += w4.x*hv.x + w4.y*hv.y + w4.z*hv.z + w4.w*hv.w;
        }
      }
#pragma unroll
      for (int s = 0; s < 16; ++s) us[s] += tanhf(d[s]) * aw;
    }
  }
#pragma unroll
  for (int s = 0; s < 16; ++s) red[s][t] = us[s];
  __syncthreads();
  for (int off = 128; off >= 1; off >>= 1) {
    if (t < off) {
#pragma unroll
      for (int s = 0; s < 16; ++s) red[s][t] += red[s][t+off];
    }
    __syncthreads();
  }
  if (t < 16) ub[b*NS + s0 + t] = red[t][0];
}

// ---- softmax + pooled + fc
__global__ __launch_bounds__(256) void k_att2(const float* __restrict__ hseq,
   const float* __restrict__ ub, const float* __restrict__ fcW,
   const float* __restrict__ fcb, float* __restrict__ out){
  __shared__ float att[NS];
  __shared__ float red[256];
  __shared__ float pool[H2];
  const int t = threadIdx.x, b = blockIdx.x;
  float v = (t < NS) ? ub[b*NS + t] : -3.4e38f;
  red[t] = v; __syncthreads();
  for (int off = 128; off >= 1; off >>= 1) {
    if (t < off) red[t] = fmaxf(red[t], red[t+off]);
    __syncthreads();
  }
  float mx = red[0]; __syncthreads();
  float e = (t < NS) ? expf(v - mx) : 0.f;
  red[t] = e; __syncthreads();
  for (int off = 128; off >= 1; off >>= 1) {
    if (t < off) red[t] += red[t+off];
    __syncthreads();
  }
  float sm = red[0]; __syncthreads();
  if (t < NS) att[t] = e / sm;
  __syncthreads();
#pragma unroll
  for (int rep = 0; rep < 2; ++rep) {
    int c = rep*256 + t;
    float acc = 0.f;
#pragma unroll 4
    for (int s = 0; s < NS; ++s) acc += att[s] * hseq[((long)b*NS + s)*H2 + c];
    pool[c] = acc;
  }
  __syncthreads();
  for (int j = 0; j < 2; ++j) {
    float p = pool[t]*fcW[j*H2+t] + pool[t+256]*fcW[j*H2+t+256];
    red[t] = p; __syncthreads();
    for (int off = 128; off >= 1; off >>= 1) {
      if (t < off) red[t] += red[t+off];
      __syncthreads();
    }
    if (t == 0) out[b*2+j] = red[0] + fcb[j];
    __syncthreads();
  }
}

extern "C" void kernel_launch(void* const* d_in, const int* in_sizes, int n_in,
                              void* d_out, int out_size, void* d_ws, size_t ws_size,
                              hipStream_t stream) {
  const int*   x     = (const int*)  d_in[0];
  const int*   z     = (const int*)  d_in[1];
  const float* emb   = (const float*)d_in[2];
  const float* Wih_f = (const float*)d_in[3];
  const float* Whh_f = (const float*)d_in[4];
  const float* bih_f = (const float*)d_in[5];
  const float* bhh_f = (const float*)d_in[6];
  const float* Wih_b = (const float*)d_in[7];
  const float* Whh_b = (const float*)d_in[8];
  const float* bih_b = (const float*)d_in[9];
  const float* bhh_b = (const float*)d_in[10];
  const float* afW   = (const float*)d_in[11];
  const float* afb   = (const float*)d_in[12];
  const float* attw  = (const float*)d_in[13];
  const float* fcW   = (const float*)d_in[14];
  const float* fcb   = (const float*)d_in[15];

  float* ws   = (float*)d_ws;
  h2_t* Wpk   = (h2_t*)ws;               // 196608 * 4B
  float* giW  = ws   + 196608;           // 8192*1536
  float* hseq = giW  + 12582912;         // 64*128*512
  float* ubuf = hseq + 4194304;          // 64*128

  k_prep<<<dim3(768), dim3(256), 0, stream>>>(Whh_f, Whh_b, Wpk);
  k_gi_mfma<<<dim3(64,12), dim3(256), 0, stream>>>(x, emb, Wih_f, Wih_b, bih_f, bih_b, giW);
  k_scan_reg<<<dim3(128), dim3(1024), 0, stream>>>(giW, Wpk, bhh_f, bhh_b, hseq);
  k_att1<<<dim3(512),  dim3(256), 0, stream>>>(hseq, afW, afb, attw, z, ubuf);
  k_att2<<<dim3(64),   dim3(256), 0, stream>>>(hseq, ubuf, fcW, fcb, (float*)d_out);
}

// Round 9
// 246.991 us; speedup vs baseline: 6.6975x; 1.4826x over previous
//
#include <hip/hip_runtime.h>
#include <math.h>

#define VEC   300
#define HID   256
#define ATT   500
#define NB    64
#define NS    128
#define G3    768     // 3*HID
#define GIC   1536    // both directions packed
#define H2    512     // 2*HID

typedef _Float16 half1;
typedef _Float16 h2_t  __attribute__((ext_vector_type(2)));
typedef _Float16 h4_t  __attribute__((ext_vector_type(4)));
typedef _Float16 f16x8 __attribute__((ext_vector_type(8)));
typedef float    f32x4 __attribute__((ext_vector_type(4)));

#if __has_builtin(__builtin_amdgcn_exp2f)
#define EXP2F(x) __builtin_amdgcn_exp2f(x)
#else
#define EXP2F(x) exp2f(x)
#endif
#if __has_builtin(__builtin_amdgcn_rcpf)
#define RCPF(x) __builtin_amdgcn_rcpf(x)
#else
#define RCPF(x) (1.0f/(x))
#endif

__device__ __forceinline__ float sigm(float x){ return RCPF(1.f + EXP2F(-1.44269504f*x)); }
__device__ __forceinline__ float tanh_fast(float x){ return 1.f - 2.f*RCPF(1.f + EXP2F(2.88539008f*x)); }

#if __has_builtin(__builtin_amdgcn_fdot2)
#define FDOT(w,h,acc) __builtin_amdgcn_fdot2((w),(h),(acc),false)
#else
#define FDOT(w,h,acc) ((acc) + (float)(w).x*(float)(h).x + (float)(w).y*(float)(h).y)
#endif

// ---- prep: pack Whh into per-thread fp16 pair layout.
__global__ __launch_bounds__(256) void k_prep(const float* __restrict__ Wf,
                       const float* __restrict__ Wb, h2_t* __restrict__ Wpk){
  int o = blockIdx.x*256 + threadIdx.x;    // < 196608
  int t = o & 1023;
  int rest = o >> 10;                      // dir*96 + p*3 + j
  int j = rest % 3;
  int p = (rest/3) & 31;
  int dir = rest / 96;
  int u = t & 255, ks = t >> 8;
  const float* W = dir ? Wb : Wf;
  int k0 = ks*64 + 2*p;
  h2_t w;
  w.x = (half1)W[(j*HID+u)*HID + k0];
  w.y = (half1)W[(j*HID+u)*HID + k0 + 1];
  Wpk[o] = w;
}

// ---- prepA: afW fp32 -> fp16, zero-padded to 512 rows.
__global__ __launch_bounds__(256) void k_prepA(const float* __restrict__ afW,
                       half1* __restrict__ afW16){
  int o = blockIdx.x*256 + threadIdx.x;    // < 262144
  int n = o >> 9, k = o & 511;
  afW16[o] = (half1)((n < ATT) ? afW[n*H2 + k] : 0.f);
}

// ---- input projection: fp16 MFMA GEMM with fused embedding gather (unchanged).
__global__ __launch_bounds__(256)
__attribute__((amdgpu_waves_per_eu(4, 4)))
void k_gi_mfma(const int* __restrict__ x,
      const float* __restrict__ emb,
      const float* __restrict__ Wf, const float* __restrict__ Wb,
      const float* __restrict__ bf, const float* __restrict__ bb,
      float* __restrict__ gi){
  __shared__ half1 Al[128*40];
  __shared__ half1 Bl[128*40];
  __shared__ int   xi[128];
  const int t = threadIdx.x;
  const int row0 = blockIdx.x * 128;
  const int col0 = blockIdx.y * 128;
  if (t < 128) {
    int i = row0 + t; int s = i >> 6; int b = i & 63;
    xi[t] = x[b*NS + s];
  }
  __syncthreads();

  const int lane = t & 63, wid = t >> 6;
  const int wr = wid >> 1, wc = wid & 1;
  const int l15 = lane & 15, lk = lane >> 4;

  f32x4 acc[4][4];
#pragma unroll
  for (int i = 0; i < 4; ++i)
#pragma unroll
    for (int j = 0; j < 4; ++j) acc[i][j] = (f32x4){0.f,0.f,0.f,0.f};

  for (int ks = 0; ks < 10; ++ks) {
#pragma unroll
    for (int l = 0; l < 8; ++l) {
      int idx = l*256 + t;
      int row = idx >> 4;
      int kp  = idx & 15;
      int kk  = ks*32 + kp*2;
      h2_t va; va.x = (half1)0.f; va.y = (half1)0.f;
      h2_t vb; vb.x = (half1)0.f; vb.y = (half1)0.f;
      if (kk < VEC) {
        float2 e = *reinterpret_cast<const float2*>(&emb[(long)xi[row]*VEC + kk]);
        va.x = (half1)e.x; va.y = (half1)e.y;
        int g = col0 + row;
        const float* W = (g < G3) ? &Wf[(long)g*VEC] : &Wb[(long)(g-G3)*VEC];
        float2 w2 = *reinterpret_cast<const float2*>(&W[kk]);
        vb.x = (half1)w2.x; vb.y = (half1)w2.y;
      }
      *reinterpret_cast<h2_t*>(&Al[row*40 + kp*2]) = va;
      *reinterpret_cast<h2_t*>(&Bl[row*40 + kp*2]) = vb;
    }
    __syncthreads();
    f16x8 af[4], bfq[4];
#pragma unroll
    for (int i = 0; i < 4; ++i)
      af[i]  = *reinterpret_cast<const f16x8*>(&Al[(wr*64 + i*16 + l15)*40 + lk*8]);
#pragma unroll
    for (int j = 0; j < 4; ++j)
      bfq[j] = *reinterpret_cast<const f16x8*>(&Bl[(wc*64 + j*16 + l15)*40 + lk*8]);
#pragma unroll
    for (int i = 0; i < 4; ++i)
#pragma unroll
      for (int j = 0; j < 4; ++j)
        acc[i][j] = __builtin_amdgcn_mfma_f32_16x16x32_f16(af[i], bfq[j], acc[i][j], 0, 0, 0);
    __syncthreads();
  }

#pragma unroll
  for (int j = 0; j < 4; ++j) {
    int gcol = col0 + wc*64 + j*16 + l15;
    float bj = (gcol < G3) ? bf[gcol] : bb[gcol - G3];
#pragma unroll
    for (int i = 0; i < 4; ++i) {
      int grow0 = row0 + wr*64 + i*16 + lk*4;
#pragma unroll
      for (int q = 0; q < 4; ++q)
        gi[(long)(grow0 + q)*GIC + gcol] = acc[i][j][q] + bj;
    }
  }
}

// ======== GRU scan: 72 named-register h2 weights + 8 pairs in LDS; b64 broadcast
// h reads; in-register hprev; exp2-based gates.
#define RP2(M) M(0,1) M(2,3) M(4,5) M(6,7) M(8,9) M(10,11) M(12,13) M(14,15) \
               M(16,17) M(18,19) M(20,21) M(22,23)
#define RPL(M) M(0) M(1) M(2) M(3) M(4) M(5) M(6) M(7) M(8) M(9) M(10) M(11) \
               M(12) M(13) M(14) M(15) M(16) M(17) M(18) M(19) M(20) M(21) M(22) M(23)

__global__ __launch_bounds__(1024)
__attribute__((amdgpu_waves_per_eu(4, 4)))
void k_scan_reg(const float* __restrict__ gi,
     const h2_t* __restrict__ Wpk,
     const float* __restrict__ bhf, const float* __restrict__ bhb,
     float* __restrict__ hseq){
  __shared__ half1 hl16[264];
  __shared__ float part[256*13];
  __shared__ h2_t  lds_w[24*1024];     // pairs 24..31, 96KB
  const int t   = threadIdx.x;
  const int u   = t & 255;
  const int ks  = t >> 8;
  const int kb  = ks * 64;
  const int dir = blockIdx.x & 1;
  const int b   = blockIdx.x >> 1;
  const float* bhh = dir ? bhb : bhf;
  const h2_t* wp = Wpk + (long)dir*96*1024 + t;

#define DECLW(p) h2_t wA##p, wB##p, wC##p;
  RPL(DECLW)
#define LOADW(p) wA##p = wp[((p)*3+0)*1024]; wB##p = wp[((p)*3+1)*1024]; wC##p = wp[((p)*3+2)*1024];
  RPL(LOADW)
#pragma unroll
  for (int q = 0; q < 24; ++q)
    lds_w[q*1024 + t] = wp[(72+q)*1024];

  float bh0=0.f, bh1=0.f, bh2=0.f;
  if (ks == 0) { bh0 = bhh[u]; bh1 = bhh[HID+u]; bh2 = bhh[2*HID+u]; }
  if (t < 256) hl16[t] = (half1)0.f;
  float hprev = 0.f;
  __syncthreads();

#pragma unroll 1
  for (int tt = 0; tt < NS; ++tt) {
    const int s = dir ? (NS-1-tt) : tt;
    float i0=0.f, i1=0.f, i2=0.f;
    if (ks == 0) {
      long base = ((long)s*NB + b)*GIC + dir*G3 + u;
      i0 = gi[base]; i1 = gi[base+HID]; i2 = gi[base+2*HID];
    }
    float a0=0.f, a1=0.f, a2=0.f;
#define FMAW2(pa,pb) { h4_t hh4 = *reinterpret_cast<const h4_t*>(&hl16[kb + 2*(pa)]); \
    h2_t lo; lo.x = hh4.x; lo.y = hh4.y; \
    h2_t hi; hi.x = hh4.z; hi.y = hh4.w; \
    a0 = FDOT(wA##pa, lo, a0); a1 = FDOT(wB##pa, lo, a1); a2 = FDOT(wC##pa, lo, a2); \
    a0 = FDOT(wA##pb, hi, a0); a1 = FDOT(wB##pb, hi, a1); a2 = FDOT(wC##pb, hi, a2); }
    RP2(FMAW2)
#pragma unroll
    for (int q = 0; q < 4; ++q) {       // LDS pairs (global 24..31): k = 48+4q..51+4q
      h4_t hh4 = *reinterpret_cast<const h4_t*>(&hl16[kb + 48 + 4*q]);
      h2_t lo; lo.x = hh4.x; lo.y = hh4.y;
      h2_t hi; hi.x = hh4.z; hi.y = hh4.w;
      h2_t w0a = lds_w[((2*q)*3+0)*1024 + t];
      h2_t w1a = lds_w[((2*q)*3+1)*1024 + t];
      h2_t w2a = lds_w[((2*q)*3+2)*1024 + t];
      h2_t w0b = lds_w[((2*q+1)*3+0)*1024 + t];
      h2_t w1b = lds_w[((2*q+1)*3+1)*1024 + t];
      h2_t w2b = lds_w[((2*q+1)*3+2)*1024 + t];
      a0 = FDOT(w0a, lo, a0); a1 = FDOT(w1a, lo, a1); a2 = FDOT(w2a, lo, a2);
      a0 = FDOT(w0b, hi, a0); a1 = FDOT(w1b, hi, a1); a2 = FDOT(w2b, hi, a2);
    }
    part[u*13 + ks*3 + 0] = a0;
    part[u*13 + ks*3 + 1] = a1;
    part[u*13 + ks*3 + 2] = a2;
    __syncthreads();
    if (ks == 0) {
      float g0 = bh0 + part[u*13+0] + part[u*13+3] + part[u*13+6] + part[u*13+9];
      float g1 = bh1 + part[u*13+1] + part[u*13+4] + part[u*13+7] + part[u*13+10];
      float g2 = bh2 + part[u*13+2] + part[u*13+5] + part[u*13+8] + part[u*13+11];
      float r  = sigm(i0 + g0);
      float zg = sigm(i1 + g1);
      float n  = tanh_fast(i2 + r*g2);
      float hn = (1.f - zg)*n + zg*hprev;
      hprev = hn;
      hl16[u] = (half1)hn;
      hseq[((long)b*NS + s)*H2 + dir*HID + u] = hn;
    }
    __syncthreads();
  }
}

// ---- attention scores via MFMA: block = (b, s-block of 32). 4 waves, each owns
// n-range of 128; A = hseq rows staged fp16 in LDS; B = afW16 frags from global.
__global__ __launch_bounds__(256)
__attribute__((amdgpu_waves_per_eu(4, 4)))
void k_att1_mfma(const float* __restrict__ hseq, const half1* __restrict__ afW16,
    const float* __restrict__ afb, const float* __restrict__ attw,
    const int* __restrict__ z, float* __restrict__ ub){
  __shared__ half1 Ah[32*520];        // 33.3KB
  __shared__ float red[4*32];
  const int t  = threadIdx.x;
  const int b  = blockIdx.x;
  const int s0 = blockIdx.y * 32;
  const int lane = t & 63, w = t >> 6;
  const int l15 = lane & 15, lk = lane >> 4;

#pragma unroll
  for (int l = 0; l < 64; ++l) {      // stage 32x512 fp32 -> fp16
    int idx = l*256 + t;
    int sl = idx >> 9, c = idx & 511;
    Ah[sl*520 + c] = (half1)hseq[((long)b*NS + s0 + sl)*H2 + c];
  }
  __syncthreads();

  f32x4 acc[2][8];
#pragma unroll
  for (int i = 0; i < 2; ++i)
#pragma unroll
    for (int j = 0; j < 8; ++j) acc[i][j] = (f32x4){0.f,0.f,0.f,0.f};

#pragma unroll 2
  for (int ksn = 0; ksn < 16; ++ksn) {
    f16x8 af[2];
#pragma unroll
    for (int mt = 0; mt < 2; ++mt)
      af[mt] = *reinterpret_cast<const f16x8*>(&Ah[(mt*16 + l15)*520 + ksn*32 + lk*8]);
#pragma unroll
    for (int nt = 0; nt < 8; ++nt) {
      int n = w*128 + nt*16 + l15;
      f16x8 bf = *reinterpret_cast<const f16x8*>(&afW16[(long)n*512 + ksn*32 + lk*8]);
#pragma unroll
      for (int mt = 0; mt < 2; ++mt)
        acc[mt][nt] = __builtin_amdgcn_mfma_f32_16x16x32_f16(af[mt], bf, acc[mt][nt], 0, 0, 0);
    }
  }

  float us[8];
#pragma unroll
  for (int i = 0; i < 8; ++i) us[i] = 0.f;
  const int zb = z[b];
#pragma unroll
  for (int nt = 0; nt < 8; ++nt) {
    int n = w*128 + nt*16 + l15;
    float ab = (n < ATT) ? afb[n] : 0.f;
    float aw = (n < ATT) ? attw[zb*ATT + n] : 0.f;
#pragma unroll
    for (int mt = 0; mt < 2; ++mt)
#pragma unroll
      for (int q = 0; q < 4; ++q)
        us[mt*4+q] += tanh_fast(acc[mt][nt][q] + ab) * aw;
  }
#pragma unroll
  for (int off = 1; off < 16; off <<= 1)
#pragma unroll
    for (int i = 0; i < 8; ++i) us[i] += __shfl_xor(us[i], off, 64);
  if (l15 == 0) {
#pragma unroll
    for (int i = 0; i < 8; ++i) {
      int row = (i >> 2)*16 + lk*4 + (i & 3);
      red[w*32 + row] = us[i];
    }
  }
  __syncthreads();
  if (t < 32)
    ub[b*NS + s0 + t] = red[t] + red[32+t] + red[64+t] + red[96+t];
}

// ---- softmax + pooled + fc
__global__ __launch_bounds__(256) void k_att2(const float* __restrict__ hseq,
   const float* __restrict__ ub, const float* __restrict__ fcW,
   const float* __restrict__ fcb, float* __restrict__ out){
  __shared__ float att[NS];
  __shared__ float red[256];
  __shared__ float pool[H2];
  const int t = threadIdx.x, b = blockIdx.x;
  float v = (t < NS) ? ub[b*NS + t] : -3.4e38f;
  red[t] = v; __syncthreads();
  for (int off = 128; off >= 1; off >>= 1) {
    if (t < off) red[t] = fmaxf(red[t], red[t+off]);
    __syncthreads();
  }
  float mx = red[0]; __syncthreads();
  float e = (t < NS) ? EXP2F(1.44269504f*(v - mx)) : 0.f;
  red[t] = e; __syncthreads();
  for (int off = 128; off >= 1; off >>= 1) {
    if (t < off) red[t] += red[t+off];
    __syncthreads();
  }
  float sm = red[0]; __syncthreads();
  if (t < NS) att[t] = e / sm;
  __syncthreads();
#pragma unroll
  for (int rep = 0; rep < 2; ++rep) {
    int c = rep*256 + t;
    float acc = 0.f;
#pragma unroll 4
    for (int s = 0; s < NS; ++s) acc += att[s] * hseq[((long)b*NS + s)*H2 + c];
    pool[c] = acc;
  }
  __syncthreads();
  for (int j = 0; j < 2; ++j) {
    float p = pool[t]*fcW[j*H2+t] + pool[t+256]*fcW[j*H2+t+256];
    red[t] = p; __syncthreads();
    for (int off = 128; off >= 1; off >>= 1) {
      if (t < off) red[t] += red[t+off];
      __syncthreads();
    }
    if (t == 0) out[b*2+j] = red[0] + fcb[j];
    __syncthreads();
  }
}

extern "C" void kernel_launch(void* const* d_in, const int* in_sizes, int n_in,
                              void* d_out, int out_size, void* d_ws, size_t ws_size,
                              hipStream_t stream) {
  const int*   x     = (const int*)  d_in[0];
  const int*   z     = (const int*)  d_in[1];
  const float* emb   = (const float*)d_in[2];
  const float* Wih_f = (const float*)d_in[3];
  const float* Whh_f = (const float*)d_in[4];
  const float* bih_f = (const float*)d_in[5];
  const float* bhh_f = (const float*)d_in[6];
  const float* Wih_b = (const float*)d_in[7];
  const float* Whh_b = (const float*)d_in[8];
  const float* bih_b = (const float*)d_in[9];
  const float* bhh_b = (const float*)d_in[10];
  const float* afW   = (const float*)d_in[11];
  const float* afb   = (const float*)d_in[12];
  const float* attw  = (const float*)d_in[13];
  const float* fcW   = (const float*)d_in[14];
  const float* fcb   = (const float*)d_in[15];

  float* ws    = (float*)d_ws;
  h2_t*  Wpk   = (h2_t*)ws;                        // 196608 * 4B
  half1* afW16 = (half1*)(ws + 196608);            // 512*512 halves = 131072 floats
  float* giW   = ws   + 196608 + 131072;           // 8192*1536
  float* hseq  = giW  + 12582912;                  // 64*128*512
  float* ubuf  = hseq + 4194304;                   // 64*128

  k_prep <<<dim3(768),  dim3(256), 0, stream>>>(Whh_f, Whh_b, Wpk);
  k_prepA<<<dim3(1024), dim3(256), 0, stream>>>(afW, afW16);
  k_gi_mfma<<<dim3(64,12), dim3(256), 0, stream>>>(x, emb, Wih_f, Wih_b, bih_f, bih_b, giW);
  k_scan_reg<<<dim3(128), dim3(1024), 0, stream>>>(giW, Wpk, bhh_f, bhh_b, hseq);
  k_att1_mfma<<<dim3(64,4), dim3(256), 0, stream>>>(hseq, afW16, afb, attw, z, ubuf);
  k_att2<<<dim3(64), dim3(256), 0, stream>>>(hseq, ubuf, fcW, fcb, (float*)d_out);
}

// Round 11
// 233.833 us; speedup vs baseline: 7.0744x; 1.0563x over previous
//
#include <hip/hip_runtime.h>
#include <math.h>

#define VEC   300
#define HID   256
#define ATT   500
#define NB    64
#define NS    128
#define G3    768     // 3*HID
#define GIC   1536    // both directions packed
#define H2    512     // 2*HID

typedef _Float16 half1;
typedef _Float16 h2_t  __attribute__((ext_vector_type(2)));
typedef _Float16 f16x8 __attribute__((ext_vector_type(8)));
typedef float    f32x4 __attribute__((ext_vector_type(4)));

struct __align__(16) H8 { h2_t a, b, c, d; };

#if __has_builtin(__builtin_amdgcn_exp2f)
#define EXP2F(x) __builtin_amdgcn_exp2f(x)
#else
#define EXP2F(x) exp2f(x)
#endif
#if __has_builtin(__builtin_amdgcn_rcpf)
#define RCPF(x) __builtin_amdgcn_rcpf(x)
#else
#define RCPF(x) (1.0f/(x))
#endif

__device__ __forceinline__ float sigm(float x){ return RCPF(1.f + EXP2F(-1.44269504f*x)); }
__device__ __forceinline__ float tanh_fast(float x){ return 1.f - 2.f*RCPF(1.f + EXP2F(2.88539008f*x)); }

#if __has_builtin(__builtin_amdgcn_fdot2)
#define FDOT(w,h,acc) __builtin_amdgcn_fdot2((w),(h),(acc),false)
#else
#define FDOT(w,h,acc) ((acc) + (float)(w).x*(float)(h).x + (float)(w).y*(float)(h).y)
#endif

// ---- prep: pack Whh into per-thread fp16 pair layout (1024-slot indexing,
// consumed by the 512-thread scan via two slice pointers).
__global__ __launch_bounds__(256) void k_prep(const float* __restrict__ Wf,
                       const float* __restrict__ Wb, h2_t* __restrict__ Wpk){
  int o = blockIdx.x*256 + threadIdx.x;    // < 196608
  int t = o & 1023;
  int rest = o >> 10;                      // dir*96 + p*3 + j
  int j = rest % 3;
  int p = (rest/3) & 31;
  int dir = rest / 96;
  int u = t & 255, ks = t >> 8;
  const float* W = dir ? Wb : Wf;
  int k0 = ks*64 + 2*p;
  h2_t w;
  w.x = (half1)W[(j*HID+u)*HID + k0];
  w.y = (half1)W[(j*HID+u)*HID + k0 + 1];
  Wpk[o] = w;
}

// ---- prepA: afW fp32 -> fp16, zero-padded to 512 rows.
__global__ __launch_bounds__(256) void k_prepA(const float* __restrict__ afW,
                       half1* __restrict__ afW16){
  int o = blockIdx.x*256 + threadIdx.x;    // < 262144
  int n = o >> 9, k = o & 511;
  afW16[o] = (half1)((n < ATT) ? afW[n*H2 + k] : 0.f);
}

// ---- input projection: fp16 MFMA GEMM with fused embedding gather (unchanged).
__global__ __launch_bounds__(256)
__attribute__((amdgpu_waves_per_eu(4, 4)))
void k_gi_mfma(const int* __restrict__ x,
      const float* __restrict__ emb,
      const float* __restrict__ Wf, const float* __restrict__ Wb,
      const float* __restrict__ bf, const float* __restrict__ bb,
      float* __restrict__ gi){
  __shared__ half1 Al[128*40];
  __shared__ half1 Bl[128*40];
  __shared__ int   xi[128];
  const int t = threadIdx.x;
  const int row0 = blockIdx.x * 128;
  const int col0 = blockIdx.y * 128;
  if (t < 128) {
    int i = row0 + t; int s = i >> 6; int b = i & 63;
    xi[t] = x[b*NS + s];
  }
  __syncthreads();

  const int lane = t & 63, wid = t >> 6;
  const int wr = wid >> 1, wc = wid & 1;
  const int l15 = lane & 15, lk = lane >> 4;

  f32x4 acc[4][4];
#pragma unroll
  for (int i = 0; i < 4; ++i)
#pragma unroll
    for (int j = 0; j < 4; ++j) acc[i][j] = (f32x4){0.f,0.f,0.f,0.f};

  for (int ks = 0; ks < 10; ++ks) {
#pragma unroll
    for (int l = 0; l < 8; ++l) {
      int idx = l*256 + t;
      int row = idx >> 4;
      int kp  = idx & 15;
      int kk  = ks*32 + kp*2;
      h2_t va; va.x = (half1)0.f; va.y = (half1)0.f;
      h2_t vb; vb.x = (half1)0.f; vb.y = (half1)0.f;
      if (kk < VEC) {
        float2 e = *reinterpret_cast<const float2*>(&emb[(long)xi[row]*VEC + kk]);
        va.x = (half1)e.x; va.y = (half1)e.y;
        int g = col0 + row;
        const float* W = (g < G3) ? &Wf[(long)g*VEC] : &Wb[(long)(g-G3)*VEC];
        float2 w2 = *reinterpret_cast<const float2*>(&W[kk]);
        vb.x = (half1)w2.x; vb.y = (half1)w2.y;
      }
      *reinterpret_cast<h2_t*>(&Al[row*40 + kp*2]) = va;
      *reinterpret_cast<h2_t*>(&Bl[row*40 + kp*2]) = vb;
    }
    __syncthreads();
    f16x8 af[4], bfq[4];
#pragma unroll
    for (int i = 0; i < 4; ++i)
      af[i]  = *reinterpret_cast<const f16x8*>(&Al[(wr*64 + i*16 + l15)*40 + lk*8]);
#pragma unroll
    for (int j = 0; j < 4; ++j)
      bfq[j] = *reinterpret_cast<const f16x8*>(&Bl[(wc*64 + j*16 + l15)*40 + lk*8]);
#pragma unroll
    for (int i = 0; i < 4; ++i)
#pragma unroll
      for (int j = 0; j < 4; ++j)
        acc[i][j] = __builtin_amdgcn_mfma_f32_16x16x32_f16(af[i], bfq[j], acc[i][j], 0, 0, 0);
    __syncthreads();
  }

#pragma unroll
  for (int j = 0; j < 4; ++j) {
    int gcol = col0 + wc*64 + j*16 + l15;
    float bj = (gcol < G3) ? bf[gcol] : bb[gcol - G3];
#pragma unroll
    for (int i = 0; i < 4; ++i) {
      int grow0 = row0 + wr*64 + i*16 + lk*4;
#pragma unroll
      for (int q = 0; q < 4; ++q)
        gi[(long)(grow0 + q)*GIC + gcol] = acc[i][j][q] + bj;
    }
  }
}

// ======== GRU scan v2: ALL 96 weight pairs per thread in 192 named h2 registers.
// 512 thr = 256 u x 2 k-slices (128 rows each); one (b,dir) per WG -> 128 WGs.
// No LDS weights; h broadcast via 16x ds_read_b128; 2 waves/SIMD (256-reg budget).
#define DECL12(X,g,UNUSED) h2_t X##g##a0,X##g##a1,X##g##a2, X##g##b0,X##g##b1,X##g##b2, \
                                X##g##c0,X##g##c1,X##g##c2, X##g##d0,X##g##d1,X##g##d2;
#define LOAD12(X,g,WP) \
  X##g##a0=(WP)[((4*(g)+0)*3+0)*1024]; X##g##a1=(WP)[((4*(g)+0)*3+1)*1024]; X##g##a2=(WP)[((4*(g)+0)*3+2)*1024]; \
  X##g##b0=(WP)[((4*(g)+1)*3+0)*1024]; X##g##b1=(WP)[((4*(g)+1)*3+1)*1024]; X##g##b2=(WP)[((4*(g)+1)*3+2)*1024]; \
  X##g##c0=(WP)[((4*(g)+2)*3+0)*1024]; X##g##c1=(WP)[((4*(g)+2)*3+1)*1024]; X##g##c2=(WP)[((4*(g)+2)*3+2)*1024]; \
  X##g##d0=(WP)[((4*(g)+3)*3+0)*1024]; X##g##d1=(WP)[((4*(g)+3)*3+1)*1024]; X##g##d2=(WP)[((4*(g)+3)*3+2)*1024];
#define FMA12(X,g,BOFF) { \
  H8 hv = *reinterpret_cast<const H8*>(&hl16[kb + (BOFF) + (g)*8]); \
  a0=FDOT(X##g##a0,hv.a,a0); a1=FDOT(X##g##a1,hv.a,a1); a2=FDOT(X##g##a2,hv.a,a2); \
  a0=FDOT(X##g##b0,hv.b,a0); a1=FDOT(X##g##b1,hv.b,a1); a2=FDOT(X##g##b2,hv.b,a2); \
  a0=FDOT(X##g##c0,hv.c,a0); a1=FDOT(X##g##c1,hv.c,a1); a2=FDOT(X##g##c2,hv.c,a2); \
  a0=FDOT(X##g##d0,hv.d,a0); a1=FDOT(X##g##d1,hv.d,a1); a2=FDOT(X##g##d2,hv.d,a2); }
#define GRP8(M,X,A2) M(X,0,A2) M(X,1,A2) M(X,2,A2) M(X,3,A2) M(X,4,A2) M(X,5,A2) M(X,6,A2) M(X,7,A2)

__global__ __launch_bounds__(512)
__attribute__((amdgpu_waves_per_eu(2, 2)))
void k_scan_reg2(const float* __restrict__ gi,
     const h2_t* __restrict__ Wpk,
     const float* __restrict__ bhf, const float* __restrict__ bhb,
     float* __restrict__ hseq){
  __shared__ __align__(16) half1 hl16[264];
  __shared__ float part[3*256];
  const int t   = threadIdx.x;
  const int u   = t & 255;
  const int ks  = t >> 8;            // 0 or 1
  const int kb  = ks * 128;
  const int dir = blockIdx.x & 1;
  const int b   = blockIdx.x >> 1;
  const float* bhh = dir ? bhb : bhf;
  const h2_t* wpA = Wpk + (long)dir*96*1024 + (2*ks)*256 + u;     // old slice 2ks
  const h2_t* wpB = Wpk + (long)dir*96*1024 + (2*ks+1)*256 + u;   // old slice 2ks+1

  GRP8(DECL12, A, 0)
  GRP8(DECL12, B, 0)
  GRP8(LOAD12, A, wpA)
  GRP8(LOAD12, B, wpB)

  float bh0=0.f, bh1=0.f, bh2=0.f;
  if (ks == 0) { bh0 = bhh[u]; bh1 = bhh[HID+u]; bh2 = bhh[2*HID+u]; }
  if (t < 256) hl16[t] = (half1)0.f;
  float hprev = 0.f;
  __syncthreads();

#pragma unroll 1
  for (int tt = 0; tt < NS; ++tt) {
    const int s = dir ? (NS-1-tt) : tt;
    float i0=0.f, i1=0.f, i2=0.f;
    if (ks == 0) {                   // issue early; consumed after the dot phase
      long base = ((long)s*NB + b)*GIC + dir*G3 + u;
      i0 = gi[base]; i1 = gi[base+HID]; i2 = gi[base+2*HID];
    }
    float a0=0.f, a1=0.f, a2=0.f;
    GRP8(FMA12, A, 0)                // rows kb+0..63
    GRP8(FMA12, B, 64)               // rows kb+64..127
    if (ks == 1) { part[u] = a0; part[256+u] = a1; part[512+u] = a2; }
    __syncthreads();
    if (ks == 0) {
      float g0 = bh0 + a0 + part[u];
      float g1 = bh1 + a1 + part[256+u];
      float g2 = bh2 + a2 + part[512+u];
      float r  = sigm(i0 + g0);
      float zg = sigm(i1 + g1);
      float n  = tanh_fast(i2 + r*g2);
      float hn = (1.f - zg)*n + zg*hprev;
      hprev = hn;
      hl16[u] = (half1)hn;
      hseq[((long)b*NS + s)*H2 + dir*HID + u] = hn;
    }
    __syncthreads();
  }
}

// ---- attention scores via MFMA (unchanged).
__global__ __launch_bounds__(256)
__attribute__((amdgpu_waves_per_eu(4, 4)))
void k_att1_mfma(const float* __restrict__ hseq, const half1* __restrict__ afW16,
    const float* __restrict__ afb, const float* __restrict__ attw,
    const int* __restrict__ z, float* __restrict__ ub){
  __shared__ half1 Ah[32*520];
  __shared__ float red[4*32];
  const int t  = threadIdx.x;
  const int b  = blockIdx.x;
  const int s0 = blockIdx.y * 32;
  const int lane = t & 63, w = t >> 6;
  const int l15 = lane & 15, lk = lane >> 4;

#pragma unroll
  for (int l = 0; l < 64; ++l) {
    int idx = l*256 + t;
    int sl = idx >> 9, c = idx & 511;
    Ah[sl*520 + c] = (half1)hseq[((long)b*NS + s0 + sl)*H2 + c];
  }
  __syncthreads();

  f32x4 acc[2][8];
#pragma unroll
  for (int i = 0; i < 2; ++i)
#pragma unroll
    for (int j = 0; j < 8; ++j) acc[i][j] = (f32x4){0.f,0.f,0.f,0.f};

#pragma unroll 2
  for (int ksn = 0; ksn < 16; ++ksn) {
    f16x8 af[2];
#pragma unroll
    for (int mt = 0; mt < 2; ++mt)
      af[mt] = *reinterpret_cast<const f16x8*>(&Ah[(mt*16 + l15)*520 + ksn*32 + lk*8]);
#pragma unroll
    for (int nt = 0; nt < 8; ++nt) {
      int n = w*128 + nt*16 + l15;
      f16x8 bf = *reinterpret_cast<const f16x8*>(&afW16[(long)n*512 + ksn*32 + lk*8]);
#pragma unroll
      for (int mt = 0; mt < 2; ++mt)
        acc[mt][nt] = __builtin_amdgcn_mfma_f32_16x16x32_f16(af[mt], bf, acc[mt][nt], 0, 0, 0);
    }
  }

  float us[8];
#pragma unroll
  for (int i = 0; i < 8; ++i) us[i] = 0.f;
  const int zb = z[b];
#pragma unroll
  for (int nt = 0; nt < 8; ++nt) {
    int n = w*128 + nt*16 + l15;
    float ab = (n < ATT) ? afb[n] : 0.f;
    float aw = (n < ATT) ? attw[zb*ATT + n] : 0.f;
#pragma unroll
    for (int mt = 0; mt < 2; ++mt)
#pragma unroll
      for (int q = 0; q < 4; ++q)
        us[mt*4+q] += tanh_fast(acc[mt][nt][q] + ab) * aw;
  }
#pragma unroll
  for (int off = 1; off < 16; off <<= 1)
#pragma unroll
    for (int i = 0; i < 8; ++i) us[i] += __shfl_xor(us[i], off, 64);
  if (l15 == 0) {
#pragma unroll
    for (int i = 0; i < 8; ++i) {
      int row = (i >> 2)*16 + lk*4 + (i & 3);
      red[w*32 + row] = us[i];
    }
  }
  __syncthreads();
  if (t < 32)
    ub[b*NS + s0 + t] = red[t] + red[32+t] + red[64+t] + red[96+t];
}

// ---- softmax + pooled + fc (unchanged)
__global__ __launch_bounds__(256) void k_att2(const float* __restrict__ hseq,
   const float* __restrict__ ub, const float* __restrict__ fcW,
   const float* __restrict__ fcb, float* __restrict__ out){
  __shared__ float att[NS];
  __shared__ float red[256];
  __shared__ float pool[H2];
  const int t = threadIdx.x, b = blockIdx.x;
  float v = (t < NS) ? ub[b*NS + t] : -3.4e38f;
  red[t] = v; __syncthreads();
  for (int off = 128; off >= 1; off >>= 1) {
    if (t < off) red[t] = fmaxf(red[t], red[t+off]);
    __syncthreads();
  }
  float mx = red[0]; __syncthreads();
  float e = (t < NS) ? EXP2F(1.44269504f*(v - mx)) : 0.f;
  red[t] = e; __syncthreads();
  for (int off = 128; off >= 1; off >>= 1) {
    if (t < off) red[t] += red[t+off];
    __syncthreads();
  }
  float sm = red[0]; __syncthreads();
  if (t < NS) att[t] = e / sm;
  __syncthreads();
#pragma unroll
  for (int rep = 0; rep < 2; ++rep) {
    int c = rep*256 + t;
    float acc = 0.f;
#pragma unroll 4
    for (int s = 0; s < NS; ++s) acc += att[s] * hseq[((long)b*NS + s)*H2 + c];
    pool[c] = acc;
  }
  __syncthreads();
  for (int j = 0; j < 2; ++j) {
    float p = pool[t]*fcW[j*H2+t] + pool[t+256]*fcW[j*H2+t+256];
    red[t] = p; __syncthreads();
    for (int off = 128; off >= 1; off >>= 1) {
      if (t < off) red[t] += red[t+off];
      __syncthreads();
    }
    if (t == 0) out[b*2+j] = red[0] + fcb[j];
    __syncthreads();
  }
}

extern "C" void kernel_launch(void* const* d_in, const int* in_sizes, int n_in,
                              void* d_out, int out_size, void* d_ws, size_t ws_size,
                              hipStream_t stream) {
  const int*   x     = (const int*)  d_in[0];
  const int*   z     = (const int*)  d_in[1];
  const float* emb   = (const float*)d_in[2];
  const float* Wih_f = (const float*)d_in[3];
  const float* Whh_f = (const float*)d_in[4];
  const float* bih_f = (const float*)d_in[5];
  const float* bhh_f = (const float*)d_in[6];
  const float* Wih_b = (const float*)d_in[7];
  const float* Whh_b = (const float*)d_in[8];
  const float* bih_b = (const float*)d_in[9];
  const float* bhh_b = (const float*)d_in[10];
  const float* afW   = (const float*)d_in[11];
  const float* afb   = (const float*)d_in[12];
  const float* attw  = (const float*)d_in[13];
  const float* fcW   = (const float*)d_in[14];
  const float* fcb   = (const float*)d_in[15];

  float* ws    = (float*)d_ws;
  h2_t*  Wpk   = (h2_t*)ws;                        // 196608 * 4B
  half1* afW16 = (half1*)(ws + 196608);            // 512*512 halves
  float* giW   = ws   + 196608 + 131072;           // 8192*1536
  float* hseq  = giW  + 12582912;                  // 64*128*512
  float* ubuf  = hseq + 4194304;                   // 64*128

  k_prep <<<dim3(768),  dim3(256), 0, stream>>>(Whh_f, Whh_b, Wpk);
  k_prepA<<<dim3(1024), dim3(256), 0, stream>>>(afW, afW16);
  k_gi_mfma<<<dim3(64,12), dim3(256), 0, stream>>>(x, emb, Wih_f, Wih_b, bih_f, bih_b, giW);
  k_scan_reg2<<<dim3(128), dim3(512), 0, stream>>>(giW, Wpk, bhh_f, bhh_b, hseq);
  k_att1_mfma<<<dim3(64,4), dim3(256), 0, stream>>>(hseq, afW16, afb, attw, z, ubuf);
  k_att2<<<dim3(64), dim3(256), 0, stream>>>(hseq, ubuf, fcW, fcb, (float*)d_out);
}